// Round 15
// baseline (257.283 us; speedup 1.0000x reference)
//
#include <hip/hip_runtime.h>
#include <math.h>

// ---------------------------------------------------------------------------
// SparseMHA, round 15 (head-per-XCD partitioning):
//   prep: W^T bf16 + bias concat + CSR row_ptr
//   convert_bf16: h -> hb
//   gemm<0>: hb via global_load_lds -> HEAD-MAJOR planes:
//     q8h[head][n][32] int8 + qs8[head][n] f32
//     kvh[head][n][64]: k int8 [0,32) + v uint8 biased [32,64)
//     ks8[head][n], vs8[head][n] f32
//   fused_attn: one wave = one (node, head); head = blockIdx.x & 7 pins each
//     head to one XCD (measured round-robin) -> per-XCD gather set ~3.8MB,
//     fits 4MB L2. Lane = 16 edge slots x 4 dim groups; sdot4 scores.
//   gemm<1>: out = aggb @ Wo + bo (f32)
// ---------------------------------------------------------------------------

typedef __attribute__((ext_vector_type(8))) short bf16x8;
typedef __attribute__((ext_vector_type(4))) float f32x4;

__device__ __forceinline__ ushort f2bf(float f) {           // RNE f32->bf16
    uint u = __float_as_uint(f);
    u += 0x7fffu + ((u >> 16) & 1u);
    return (ushort)(u >> 16);
}
__device__ __forceinline__ float bflo(uint u) { return __uint_as_float(u << 16); }
__device__ __forceinline__ float bfhi(uint u) { return __uint_as_float(u & 0xffff0000u); }

#if __has_builtin(__builtin_amdgcn_sdot4)
__device__ __forceinline__ int SDOT4(uint a, uint b, int c) {
    return __builtin_amdgcn_sdot4((int)a, (int)b, c, false);
}
#else
__device__ __forceinline__ int SDOT4(uint a, uint b, int c) {
    #pragma unroll
    for (int i = 0; i < 4; ++i)
        c += ((int)(a << (24 - 8 * i)) >> 24) * ((int)(b << (24 - 8 * i)) >> 24);
    return c;
}
#endif

__device__ __forceinline__ void load_lds16(const void* g, void* l) {
    __builtin_amdgcn_global_load_lds(
        (const __attribute__((address_space(1))) void*)g,
        (__attribute__((address_space(3))) void*)l, 16, 0, 0);
}

// f32 -> bf16 elementwise (h)
__global__ __launch_bounds__(256) void convert_bf16(
    const float* __restrict__ in, ushort* __restrict__ out, size_t nelem)
{
    size_t i = ((size_t)blockIdx.x * 256 + threadIdx.x) * 4;
    if (i >= nelem) return;
    float4 v = *(const float4*)(in + i);
    *(ushort4*)(out + i) = make_ushort4(f2bf(v.x), f2bf(v.y), f2bf(v.z), f2bf(v.w));
}

// All prep in one launch: grid (257, 5).
__global__ __launch_bounds__(256) void prep(
    const float* __restrict__ Wq, const float* __restrict__ Wk,
    const float* __restrict__ Wv, const float* __restrict__ Wo,
    const float* __restrict__ bq, const float* __restrict__ bk,
    const float* __restrict__ bv,
    const int* __restrict__ row, int* __restrict__ row_ptr, int n, int E,
    ushort* __restrict__ Wall, ushort* __restrict__ Wot,
    float* __restrict__ ball)
{
    int m = blockIdx.y;
    if (m == 4) {
        int i = blockIdx.x * 256 + threadIdx.x;
        if (i > n) return;
        int lo = 0, hi = E;
        while (lo < hi) {
            int mid = (lo + hi) >> 1;
            if (row[mid] < i) lo = mid + 1; else hi = mid;
        }
        row_ptr[i] = lo;
        return;
    }
    if (blockIdx.x < 256) {
        int idx = blockIdx.x * 256 + threadIdx.x;   // idx = k*256 + nn
        int k = idx >> 8, nn = idx & 255;
        if (m < 3) {
            const float* W = m == 0 ? Wq : (m == 1 ? Wk : Wv);
            Wall[((size_t)m * 256 + nn) * 256 + k] = f2bf(W[idx]);
        } else {
            Wot[nn * 256 + k] = f2bf(Wo[idx]);
        }
    } else if (m < 3) {
        int i = threadIdx.x;
        ball[m * 256 + i] = (m == 0 ? bq : (m == 1 ? bk : bv))[i];
    }
}

// ---------------------------------------------------------------------------
// LDS-staged MFMA GEMM (m97 structure), 128x128 tiles, grid (6|2, mtiles).
// MODE 0 (QKV): tiles 0,1 -> q8h+qs8; 2,3 -> kvh k-half + ks8;
//               4,5 -> kvh v-half + vs8. All head-major planes.
// MODE 1 (out): f32 direct stores.
// ---------------------------------------------------------------------------
template<int MODE>
__global__ __launch_bounds__(256) void gemm_mfma_lds(
    const ushort* __restrict__ A, const ushort* __restrict__ Wt,
    const float* __restrict__ bias, char* __restrict__ q8h,
    float* __restrict__ qs8, uchar* __restrict__ kvh,
    float* __restrict__ ks8, float* __restrict__ vs8,
    float* __restrict__ outf, int n, float scale)
{
    __shared__ ushort SH[2 * 128 * 64];          // As | Bs, reused by epilogue
    ushort* As = SH;
    ushort* Bs = SH + 128 * 64;

    const int nwg = gridDim.x * gridDim.y;
    const int orig = blockIdx.y * gridDim.x + blockIdx.x;
    const int xcd = orig & 7, rnd = orig >> 3;
    const int q8 = nwg >> 3, r8 = nwg & 7;
    const int wgid = (xcd < r8 ? xcd * (q8 + 1) : r8 * (q8 + 1) + (xcd - r8) * q8) + rnd;
    const int tx = wgid % gridDim.x;
    const int ty = wgid / gridDim.x;

    const int tid = threadIdx.x;
    const int lane = tid & 63;
    const int wave = tid >> 6;
    const int col0 = tx * 128;
    const int row0 = ty * 128;
    const int fr = lane & 15;
    const int kg = lane >> 4;
    const int wr = (wave >> 1) * 64;
    const int wc = (wave & 1) * 64;

    f32x4 acc[4][4] = {};

    const int srow = tid >> 3;
    const int sc8 = tid & 7;

    for (int kt = 0; kt < 4; ++kt) {
        #pragma unroll
        for (int it = 0; it < 4; ++it) {
            int r = srow + it * 32;
            int chunk = sc8 ^ (r & 7);
            int ar = row0 + r; ar = ar < n ? ar : n - 1;
            load_lds16((const char*)A + (size_t)ar * 512 + kt * 128 + chunk * 16,
                       (char*)As + (it * 256 + tid) * 16);
            load_lds16((const char*)Wt + (size_t)(col0 + r) * 512 + kt * 128 + chunk * 16,
                       (char*)Bs + (it * 256 + tid) * 16);
        }
        __syncthreads();

        #pragma unroll
        for (int ks = 0; ks < 2; ++ks) {
            bf16x8 a[4], b[4];
            #pragma unroll
            for (int i = 0; i < 4; ++i) {
                int r = wr + i * 16 + fr;
                int chunk = (ks * 4 + kg) ^ (r & 7);
                a[i] = *(const bf16x8*)((const char*)As + r * 128 + chunk * 16);
            }
            #pragma unroll
            for (int j = 0; j < 4; ++j) {
                int c = wc + j * 16 + fr;
                int chunk = (ks * 4 + kg) ^ (c & 7);
                b[j] = *(const bf16x8*)((const char*)Bs + c * 128 + chunk * 16);
            }
            #pragma unroll
            for (int i = 0; i < 4; ++i)
                #pragma unroll
                for (int j = 0; j < 4; ++j)
                    acc[i][j] = __builtin_amdgcn_mfma_f32_16x16x32_bf16(
                        a[i], b[j], acc[i][j], 0, 0, 0);
        }
        __syncthreads();
    }

    if constexpr (MODE == 1) {
        #pragma unroll
        for (int j = 0; j < 4; ++j) {
            int gcol = col0 + wc + j * 16 + fr;
            float bj = bias[gcol];
            #pragma unroll
            for (int i = 0; i < 4; ++i) {
                #pragma unroll
                for (int r = 0; r < 4; ++r) {
                    int grow = row0 + wr + i * 16 + kg * 4 + r;
                    if (grow >= n) continue;
                    outf[(size_t)grow * 256 + gcol] = acc[i][j][r] + bj;
                }
            }
        }
        return;
    }

    // ---- MODE 0 epilogue: pack bf16 to LDS (256B rows, unit-swizzled) ----
    char* sb = (char*)SH;
    const float sc = (col0 < 256) ? scale : 1.f;

    #pragma unroll
    for (int j = 0; j < 4; ++j) {
        int cw = wc + j * 16 + fr;                   // local col 0..127
        float bj = bias[col0 + cw];
        #pragma unroll
        for (int i = 0; i < 4; ++i) {
            #pragma unroll
            for (int r2 = 0; r2 < 4; ++r2) {
                int lrow = wr + i * 16 + kg * 4 + r2;
                float val = (acc[i][j][r2] + bj) * sc;
                int u = cw >> 3;
                *(ushort*)(sb + lrow * 256 + ((u ^ (lrow & 7)) << 4) +
                           ((cw & 7) << 1)) = f2bf(val);
            }
        }
    }
    __syncthreads();

    // All tiles: per (row, 32-col head) quantize -> head-major planes.
    // q: signed int8, per-head scale. k: signed int8, scale = 128-col rowmax
    // (same numerics as round 14). v: biased uint8, per-head scale.
    const bool isq = (col0 < 256);
    const bool isk = (col0 >= 256 && col0 < 512);
    const int headBase = (isq ? col0 : (isk ? col0 - 256 : col0 - 512)) >> 5;

    #pragma unroll
    for (int pass = 0; pass < 2; ++pass) {
        int t = pass * 256 + tid;
        int lrow = t >> 2, hh = t & 3;
        float vals[32];
        #pragma unroll
        for (int uu = 0; uu < 4; ++uu) {
            int u = hh * 4 + uu;
            uint4 d = *(const uint4*)(sb + lrow * 256 + ((u ^ (lrow & 7)) << 4));
            vals[uu*8+0] = bflo(d.x); vals[uu*8+1] = bfhi(d.x);
            vals[uu*8+2] = bflo(d.y); vals[uu*8+3] = bfhi(d.y);
            vals[uu*8+4] = bflo(d.z); vals[uu*8+5] = bfhi(d.z);
            vals[uu*8+6] = bflo(d.w); vals[uu*8+7] = bfhi(d.w);
        }
        float mx = 0.f;
        #pragma unroll
        for (int i = 0; i < 32; ++i) mx = fmaxf(mx, fabsf(vals[i]));
        if (isk) {   // k scale = rowmax over full 128-col half (round-14 numerics)
            mx = fmaxf(mx, __shfl_xor(mx, 1));
            mx = fmaxf(mx, __shfl_xor(mx, 2));
        }
        float inv = mx > 0.f ? 127.f / mx : 0.f;
        float scl = mx > 0.f ? mx * (1.f / 127.f) : 0.f;
        uint pk[8];
        #pragma unroll
        for (int w = 0; w < 8; ++w) {
            int b0 = __float2int_rn(vals[w*4+0] * inv);
            int b1 = __float2int_rn(vals[w*4+1] * inv);
            int b2 = __float2int_rn(vals[w*4+2] * inv);
            int b3 = __float2int_rn(vals[w*4+3] * inv);
            if (!isq && !isk) { b0 += 128; b1 += 128; b2 += 128; b3 += 128; }
            pk[w] = ((uint)b0 & 0xff) | (((uint)b1 & 0xff) << 8) |
                    (((uint)b2 & 0xff) << 16) | (((uint)b3 & 0xff) << 24);
        }
        int grow = row0 + lrow;
        if (grow < n) {
            size_t plane = ((size_t)(headBase + hh)) * n + grow;
            char* dst;
            if (isq)      dst = q8h + plane * 32;
            else if (isk) dst = (char*)kvh + plane * 64;
            else          dst = (char*)kvh + plane * 64 + 32;
            *(uint4*)dst        = make_uint4(pk[0], pk[1], pk[2], pk[3]);
            *(uint4*)(dst + 16) = make_uint4(pk[4], pk[5], pk[6], pk[7]);
            (isq ? qs8 : (isk ? ks8 : vs8))[plane] = scl;
        }
    }
}

// Fused SDDMM + softmax + SpMM, head-partitioned.
// One wave = one (node, head); head = blockIdx.x & 7 -> pins head to XCD.
// Lane = slot(16) x dim-group(4, 8 dims each). kvh row 64B: k int8 + v uint8.
__global__ __launch_bounds__(256) void fused_attn(
    const char* __restrict__ q8h, const float* __restrict__ qs8,
    const uchar* __restrict__ kvh, const float* __restrict__ ks8,
    const float* __restrict__ vs8, const int* __restrict__ col,
    const int* __restrict__ row_ptr, ushort* __restrict__ agg, int n)
{
    const int head = blockIdx.x & 7;
    const int node = (blockIdx.x >> 3) * 4 + (threadIdx.x >> 6);
    if (node >= n) return;
    const int lane = threadIdx.x & 63;
    const int p0 = row_ptr[node], p1 = row_ptr[node + 1];

    const int slot = lane >> 2;          // 0..15 edge slot
    const int dg = lane & 3;             // dims [dg*8, dg*8+8)

    const size_t hbase = (size_t)head * n;
    uint2 qi = *(const uint2*)(q8h + (hbase + node) * 32 + dg * 8);
    float qs = qs8[hbase + node];

    float denom = 0.f;
    float cacc = 0.f;
    float acc[8] = {};

#define ISSUE(IDX, K, V, KS, VS)                                               \
    do {                                                                       \
        int src_ = __shfl(cl, (IDX));                                          \
        const char* b_ = (const char*)kvh + (hbase + src_) * 64;               \
        K = *(const uint2*)(b_ + dg * 8);                                      \
        V = *(const uint2*)(b_ + 32 + dg * 8);                                 \
        KS = ks8[hbase + src_];                                                \
        VS = vs8[hbase + src_];                                                \
    } while (0)

#define CONSUME(VALID, K, V, KS, VS)                                           \
    do {                                                                       \
        int id_ = SDOT4(qi.x, K.x, 0);                                         \
        id_ = SDOT4(qi.y, K.y, id_);                                           \
        int t1_ = id_ + __shfl_xor(id_, 1);                                    \
        int t2_ = t1_ + __shfl_xor(t1_, 2);                                    \
        float s_ = (float)t2_ * (qs * (KS));                                   \
        float p_ = (VALID) ? __expf(s_) : 0.f;                                 \
        denom += p_;                                                           \
        float ps_ = p_ * (VS);                                                 \
        cacc += ps_;                                                           \
        uint w_;                                                               \
        w_ = V.x;                                                              \
        acc[0] = fmaf(ps_, (float)(w_ & 0xff),         acc[0]);                \
        acc[1] = fmaf(ps_, (float)((w_ >> 8) & 0xff),  acc[1]);                \
        acc[2] = fmaf(ps_, (float)((w_ >> 16) & 0xff), acc[2]);                \
        acc[3] = fmaf(ps_, (float)(w_ >> 24),          acc[3]);                \
        w_ = V.y;                                                              \
        acc[4] = fmaf(ps_, (float)(w_ & 0xff),         acc[4]);                \
        acc[5] = fmaf(ps_, (float)((w_ >> 8) & 0xff),  acc[5]);                \
        acc[6] = fmaf(ps_, (float)((w_ >> 16) & 0xff), acc[6]);                \
        acc[7] = fmaf(ps_, (float)(w_ >> 24),          acc[7]);                \
    } while (0)

    for (int bbase = p0; bbase < p1; bbase += 64) {
        int bd = min(64, p1 - bbase);
        int cl = (lane < bd) ? col[bbase + lane] : 0;
        int nch = (bd + 15) >> 4;       // 16-edge chunks

        uint2 kA, vA, kB, vB; float ksA, vsA, ksB, vsB;
        ISSUE(slot, kA, vA, ksA, vsA);
        int c = 0;
        for (;;) {
            if (c + 1 < nch) ISSUE((c + 1) * 16 + slot, kB, vB, ksB, vsB);
            CONSUME(c * 16 + slot < bd, kA, vA, ksA, vsA);
            if (++c >= nch) break;
            if (c + 1 < nch) ISSUE((c + 1) * 16 + slot, kA, vA, ksA, vsA);
            CONSUME(c * 16 + slot < bd, kB, vB, ksB, vsB);
            if (++c >= nch) break;
        }
    }
#undef ISSUE
#undef CONSUME

    // undo +128 bias, then reduce over the 16 slots (lane bits 2..5)
    #pragma unroll
    for (int i = 0; i < 8; ++i) acc[i] = fmaf(-128.f, cacc, acc[i]);
    #pragma unroll
    for (int i = 0; i < 8; ++i) {
        acc[i] += __shfl_xor(acc[i], 4);
        acc[i] += __shfl_xor(acc[i], 8);
        acc[i] += __shfl_xor(acc[i], 16);
        acc[i] += __shfl_xor(acc[i], 32);
    }
    denom += __shfl_xor(denom, 4);
    denom += __shfl_xor(denom, 8);
    denom += __shfl_xor(denom, 16);
    denom += __shfl_xor(denom, 32);

    if (slot == 0) {                     // lanes 0..3: write 16B each
        float inv = denom > 0.f ? 1.f / denom : 0.f;
        uint o[4];
        #pragma unroll
        for (int i = 0; i < 4; ++i)
            o[i] = (uint)f2bf(acc[2 * i] * inv) |
                   ((uint)f2bf(acc[2 * i + 1] * inv) << 16);
        char* ob = (char*)agg + (size_t)node * 512 + head * 64 + dg * 16;
        *(uint4*)ob = make_uint4(o[0], o[1], o[2], o[3]);
    }
}

extern "C" void kernel_launch(void* const* d_in, const int* in_sizes, int n_in,
                              void* d_out, int out_size, void* d_ws, size_t ws_size,
                              hipStream_t stream)
{
    const float* h  = (const float*)d_in[0];
    const int*   row = (const int*)d_in[1];
    const int*   col = (const int*)d_in[2];
    const float* Wq = (const float*)d_in[3];
    const float* bq = (const float*)d_in[4];
    const float* Wk = (const float*)d_in[5];
    const float* bk = (const float*)d_in[6];
    const float* Wv = (const float*)d_in[7];
    const float* bv = (const float*)d_in[8];
    const float* Wo = (const float*)d_in[9];
    const float* bo = (const float*)d_in[10];
    float* out = (float*)d_out;

    const int n = in_sizes[0] / 256;
    const int E = in_sizes[1];
    const size_t NC = (size_t)n * 256;

    char* base = (char*)d_ws;
    char*   q8h  = base;                                          // n*256 B
    uchar*  kvh  = (uchar*)(base + (size_t)n * 256);              // n*512 B
    float*  qs8  = (float*)(base + (size_t)n * 768);              // n*32 B
    float*  ks8  = (float*)(base + (size_t)n * 800);              // n*32 B
    float*  vs8  = (float*)(base + (size_t)n * 832);              // n*32 B
    ushort* aggb = (ushort*)(base + (size_t)n * 864);             // n*512 B
    ushort* hb   = (ushort*)(base + (size_t)n * 1376);            // n*512 B
    ushort* Wall = (ushort*)(base + (size_t)n * 1888);            // 384KB
    ushort* Wot  = Wall + 768 * 256;                              // 128KB
    float*  ball = (float*)(Wot + 65536);                         // 3KB
    int* row_ptr = (int*)(ball + 768);

    const float scaling = 0.17677669529663687f;  // 32^-0.5

    dim3 blk(256);
    prep<<<dim3(257, 5), blk, 0, stream>>>(Wq, Wk, Wv, Wo, bq, bk, bv,
                                           row, row_ptr, n, E,
                                           Wall, Wot, ball);
    convert_bf16<<<dim3((int)((NC / 4 + 255) / 256)), blk, 0, stream>>>(h, hb, NC);

    const int mtiles = (n + 127) / 128;
    gemm_mfma_lds<0><<<dim3(6, mtiles), blk, 0, stream>>>(
        hb, Wall, ball, q8h, qs8, kvh, ks8, vs8, nullptr, n, scaling);

    fused_attn<<<dim3(((n + 3) / 4) * 8), blk, 0, stream>>>(
        q8h, qs8, kvh, ks8, vs8, col, row_ptr, aggb, n);

    gemm_mfma_lds<1><<<dim3(2, mtiles), blk, 0, stream>>>(
        aggb, Wot, bo, nullptr, nullptr, nullptr, nullptr, nullptr, out, n, 1.f);
}

// Round 16
// 203.531 us; speedup vs baseline: 1.2641x; 1.2641x over previous
//
#include <hip/hip_runtime.h>
#include <math.h>

// ---------------------------------------------------------------------------
// SparseMHA, round 16 (head-per-XCD + 4-nodes-per-wave):
//   prep / convert_bf16 / gemm<0> head-major planes / gemm<1>: as round 15
//   fused_attn: block = (16-node group, head); head = blockIdx.x & 7 pins the
//     head's 3.6MB k/v/scale set to one XCD L2. One wave = 4 nodes x 1 head;
//     lane = nd(2b)|slot(2b)|dg(2b). Slot-reduce (shfl_xor 4,8) retires four
//     nodes per pass -> ~4x fewer ds_bpermute ops than round 15.
// ---------------------------------------------------------------------------

typedef __attribute__((ext_vector_type(8))) short bf16x8;
typedef __attribute__((ext_vector_type(4))) float f32x4;

__device__ __forceinline__ ushort f2bf(float f) {           // RNE f32->bf16
    uint u = __float_as_uint(f);
    u += 0x7fffu + ((u >> 16) & 1u);
    return (ushort)(u >> 16);
}
__device__ __forceinline__ float bflo(uint u) { return __uint_as_float(u << 16); }
__device__ __forceinline__ float bfhi(uint u) { return __uint_as_float(u & 0xffff0000u); }

#if __has_builtin(__builtin_amdgcn_sdot4)
__device__ __forceinline__ int SDOT4(uint a, uint b, int c) {
    return __builtin_amdgcn_sdot4((int)a, (int)b, c, false);
}
#else
__device__ __forceinline__ int SDOT4(uint a, uint b, int c) {
    #pragma unroll
    for (int i = 0; i < 4; ++i)
        c += ((int)(a << (24 - 8 * i)) >> 24) * ((int)(b << (24 - 8 * i)) >> 24);
    return c;
}
#endif

__device__ __forceinline__ void load_lds16(const void* g, void* l) {
    __builtin_amdgcn_global_load_lds(
        (const __attribute__((address_space(1))) void*)g,
        (__attribute__((address_space(3))) void*)l, 16, 0, 0);
}

// f32 -> bf16 elementwise (h)
__global__ __launch_bounds__(256) void convert_bf16(
    const float* __restrict__ in, ushort* __restrict__ out, size_t nelem)
{
    size_t i = ((size_t)blockIdx.x * 256 + threadIdx.x) * 4;
    if (i >= nelem) return;
    float4 v = *(const float4*)(in + i);
    *(ushort4*)(out + i) = make_ushort4(f2bf(v.x), f2bf(v.y), f2bf(v.z), f2bf(v.w));
}

// All prep in one launch: grid (257, 5).
__global__ __launch_bounds__(256) void prep(
    const float* __restrict__ Wq, const float* __restrict__ Wk,
    const float* __restrict__ Wv, const float* __restrict__ Wo,
    const float* __restrict__ bq, const float* __restrict__ bk,
    const float* __restrict__ bv,
    const int* __restrict__ row, int* __restrict__ row_ptr, int n, int E,
    ushort* __restrict__ Wall, ushort* __restrict__ Wot,
    float* __restrict__ ball)
{
    int m = blockIdx.y;
    if (m == 4) {
        int i = blockIdx.x * 256 + threadIdx.x;
        if (i > n) return;
        int lo = 0, hi = E;
        while (lo < hi) {
            int mid = (lo + hi) >> 1;
            if (row[mid] < i) lo = mid + 1; else hi = mid;
        }
        row_ptr[i] = lo;
        return;
    }
    if (blockIdx.x < 256) {
        int idx = blockIdx.x * 256 + threadIdx.x;   // idx = k*256 + nn
        int k = idx >> 8, nn = idx & 255;
        if (m < 3) {
            const float* W = m == 0 ? Wq : (m == 1 ? Wk : Wv);
            Wall[((size_t)m * 256 + nn) * 256 + k] = f2bf(W[idx]);
        } else {
            Wot[nn * 256 + k] = f2bf(Wo[idx]);
        }
    } else if (m < 3) {
        int i = threadIdx.x;
        ball[m * 256 + i] = (m == 0 ? bq : (m == 1 ? bk : bv))[i];
    }
}

// ---------------------------------------------------------------------------
// LDS-staged MFMA GEMM (m97 structure), 128x128 tiles, grid (6|2, mtiles).
// MODE 0 (QKV): tiles 0,1 -> q8h+qs8; 2,3 -> kvh k-half + ks8;
//               4,5 -> kvh v-half + vs8. All head-major planes.
// MODE 1 (out): f32 direct stores.
// ---------------------------------------------------------------------------
template<int MODE>
__global__ __launch_bounds__(256) void gemm_mfma_lds(
    const ushort* __restrict__ A, const ushort* __restrict__ Wt,
    const float* __restrict__ bias, char* __restrict__ q8h,
    float* __restrict__ qs8, uchar* __restrict__ kvh,
    float* __restrict__ ks8, float* __restrict__ vs8,
    float* __restrict__ outf, int n, float scale)
{
    __shared__ ushort SH[2 * 128 * 64];          // As | Bs, reused by epilogue
    ushort* As = SH;
    ushort* Bs = SH + 128 * 64;

    const int nwg = gridDim.x * gridDim.y;
    const int orig = blockIdx.y * gridDim.x + blockIdx.x;
    const int xcd = orig & 7, rnd = orig >> 3;
    const int q8 = nwg >> 3, r8 = nwg & 7;
    const int wgid = (xcd < r8 ? xcd * (q8 + 1) : r8 * (q8 + 1) + (xcd - r8) * q8) + rnd;
    const int tx = wgid % gridDim.x;
    const int ty = wgid / gridDim.x;

    const int tid = threadIdx.x;
    const int lane = tid & 63;
    const int wave = tid >> 6;
    const int col0 = tx * 128;
    const int row0 = ty * 128;
    const int fr = lane & 15;
    const int kg = lane >> 4;
    const int wr = (wave >> 1) * 64;
    const int wc = (wave & 1) * 64;

    f32x4 acc[4][4] = {};

    const int srow = tid >> 3;
    const int sc8 = tid & 7;

    for (int kt = 0; kt < 4; ++kt) {
        #pragma unroll
        for (int it = 0; it < 4; ++it) {
            int r = srow + it * 32;
            int chunk = sc8 ^ (r & 7);
            int ar = row0 + r; ar = ar < n ? ar : n - 1;
            load_lds16((const char*)A + (size_t)ar * 512 + kt * 128 + chunk * 16,
                       (char*)As + (it * 256 + tid) * 16);
            load_lds16((const char*)Wt + (size_t)(col0 + r) * 512 + kt * 128 + chunk * 16,
                       (char*)Bs + (it * 256 + tid) * 16);
        }
        __syncthreads();

        #pragma unroll
        for (int ks = 0; ks < 2; ++ks) {
            bf16x8 a[4], b[4];
            #pragma unroll
            for (int i = 0; i < 4; ++i) {
                int r = wr + i * 16 + fr;
                int chunk = (ks * 4 + kg) ^ (r & 7);
                a[i] = *(const bf16x8*)((const char*)As + r * 128 + chunk * 16);
            }
            #pragma unroll
            for (int j = 0; j < 4; ++j) {
                int c = wc + j * 16 + fr;
                int chunk = (ks * 4 + kg) ^ (c & 7);
                b[j] = *(const bf16x8*)((const char*)Bs + c * 128 + chunk * 16);
            }
            #pragma unroll
            for (int i = 0; i < 4; ++i)
                #pragma unroll
                for (int j = 0; j < 4; ++j)
                    acc[i][j] = __builtin_amdgcn_mfma_f32_16x16x32_bf16(
                        a[i], b[j], acc[i][j], 0, 0, 0);
        }
        __syncthreads();
    }

    if constexpr (MODE == 1) {
        #pragma unroll
        for (int j = 0; j < 4; ++j) {
            int gcol = col0 + wc + j * 16 + fr;
            float bj = bias[gcol];
            #pragma unroll
            for (int i = 0; i < 4; ++i) {
                #pragma unroll
                for (int r = 0; r < 4; ++r) {
                    int grow = row0 + wr + i * 16 + kg * 4 + r;
                    if (grow >= n) continue;
                    outf[(size_t)grow * 256 + gcol] = acc[i][j][r] + bj;
                }
            }
        }
        return;
    }

    // ---- MODE 0 epilogue: pack bf16 to LDS (256B rows, unit-swizzled) ----
    char* sb = (char*)SH;
    const float sc = (col0 < 256) ? scale : 1.f;

    #pragma unroll
    for (int j = 0; j < 4; ++j) {
        int cw = wc + j * 16 + fr;                   // local col 0..127
        float bj = bias[col0 + cw];
        #pragma unroll
        for (int i = 0; i < 4; ++i) {
            #pragma unroll
            for (int r2 = 0; r2 < 4; ++r2) {
                int lrow = wr + i * 16 + kg * 4 + r2;
                float val = (acc[i][j][r2] + bj) * sc;
                int u = cw >> 3;
                *(ushort*)(sb + lrow * 256 + ((u ^ (lrow & 7)) << 4) +
                           ((cw & 7) << 1)) = f2bf(val);
            }
        }
    }
    __syncthreads();

    // Per (row, 32-col head) quantize -> head-major planes.
    const bool isq = (col0 < 256);
    const bool isk = (col0 >= 256 && col0 < 512);
    const int headBase = (isq ? col0 : (isk ? col0 - 256 : col0 - 512)) >> 5;

    #pragma unroll
    for (int pass = 0; pass < 2; ++pass) {
        int t = pass * 256 + tid;
        int lrow = t >> 2, hh = t & 3;
        float vals[32];
        #pragma unroll
        for (int uu = 0; uu < 4; ++uu) {
            int u = hh * 4 + uu;
            uint4 d = *(const uint4*)(sb + lrow * 256 + ((u ^ (lrow & 7)) << 4));
            vals[uu*8+0] = bflo(d.x); vals[uu*8+1] = bfhi(d.x);
            vals[uu*8+2] = bflo(d.y); vals[uu*8+3] = bfhi(d.y);
            vals[uu*8+4] = bflo(d.z); vals[uu*8+5] = bfhi(d.z);
            vals[uu*8+6] = bflo(d.w); vals[uu*8+7] = bfhi(d.w);
        }
        float mx = 0.f;
        #pragma unroll
        for (int i = 0; i < 32; ++i) mx = fmaxf(mx, fabsf(vals[i]));
        if (isk) {   // k scale = rowmax over full 128-col half (round-14 numerics)
            mx = fmaxf(mx, __shfl_xor(mx, 1));
            mx = fmaxf(mx, __shfl_xor(mx, 2));
        }
        float inv = mx > 0.f ? 127.f / mx : 0.f;
        float scl = mx > 0.f ? mx * (1.f / 127.f) : 0.f;
        uint pk[8];
        #pragma unroll
        for (int w = 0; w < 8; ++w) {
            int b0 = __float2int_rn(vals[w*4+0] * inv);
            int b1 = __float2int_rn(vals[w*4+1] * inv);
            int b2 = __float2int_rn(vals[w*4+2] * inv);
            int b3 = __float2int_rn(vals[w*4+3] * inv);
            if (!isq && !isk) { b0 += 128; b1 += 128; b2 += 128; b3 += 128; }
            pk[w] = ((uint)b0 & 0xff) | (((uint)b1 & 0xff) << 8) |
                    (((uint)b2 & 0xff) << 16) | (((uint)b3 & 0xff) << 24);
        }
        int grow = row0 + lrow;
        if (grow < n) {
            size_t plane = ((size_t)(headBase + hh)) * n + grow;
            char* dst;
            if (isq)      dst = q8h + plane * 32;
            else if (isk) dst = (char*)kvh + plane * 64;
            else          dst = (char*)kvh + plane * 64 + 32;
            *(uint4*)dst        = make_uint4(pk[0], pk[1], pk[2], pk[3]);
            *(uint4*)(dst + 16) = make_uint4(pk[4], pk[5], pk[6], pk[7]);
            (isq ? qs8 : (isk ? ks8 : vs8))[plane] = scl;
        }
    }
}

// Fused SDDMM + softmax + SpMM, head-per-XCD, 4 nodes per wave.
// block = (16-node group, head); head = blockIdx.x & 7 -> XCD pinning.
// lane = nd(bits 5:4) | slot(bits 3:2) | dg(bits 1:0).
// Per chunk: 4 edges/node x 4 nodes; score dot over dg (shfl 1,2);
// epilogue slot-reduce (shfl 4,8) retires all 4 nodes in one pass.
__global__ __launch_bounds__(256) void fused_attn(
    const char* __restrict__ q8h, const float* __restrict__ qs8,
    const uchar* __restrict__ kvh, const float* __restrict__ ks8,
    const float* __restrict__ vs8, const int* __restrict__ col,
    const int* __restrict__ row_ptr, ushort* __restrict__ agg, int n)
{
    const int head = blockIdx.x & 7;
    const int wave = threadIdx.x >> 6;
    const int lane = threadIdx.x & 63;
    const int dg   = lane & 3;           // dims [dg*8, dg*8+8)
    const int slot = (lane >> 2) & 3;    // edge slot within chunk
    const int nd   = lane >> 4;          // node within wave

    const int node = (blockIdx.x >> 3) * 16 + wave * 4 + nd;
    const bool nv = node < n;
    const int nc = nv ? node : n - 1;

    const size_t hbase = (size_t)head * n;
    const int p0 = row_ptr[nc], p1 = row_ptr[nc + 1];
    const int deg = nv ? (p1 - p0) : 0;

    uint2 qi = *(const uint2*)(q8h + (hbase + nc) * 32 + dg * 8);
    float qs = qs8[hbase + nc];

    // uniform loop bound: max deg over the wave's 4 nodes (nd bits 4,5)
    int mdeg = deg;
    mdeg = max(mdeg, __shfl_xor(mdeg, 16));
    mdeg = max(mdeg, __shfl_xor(mdeg, 32));

    float denom = 0.f, cacc = 0.f;
    float acc[8] = {};

    for (int b = 0; b < mdeg; b += 16) {
        int li = lane & 15;              // 16 edges per node per batch
        int cl = (li < deg - b) ? col[p0 + b + li] : 0;

        #pragma unroll
        for (int c = 0; c < 4; ++c) {
            int srcl = (lane & 48) | (c * 4 + slot);
            int src = __shfl(cl, srcl);
            bool valid = (b + c * 4 + slot) < deg;
            const char* bp = (const char*)kvh + (hbase + src) * 64;
            uint2 K = *(const uint2*)(bp + dg * 8);
            uint2 V = *(const uint2*)(bp + 32 + dg * 8);
            float KS = ks8[hbase + src];
            float VS = vs8[hbase + src];

            int id = SDOT4(qi.x, K.x, 0);
            id = SDOT4(qi.y, K.y, id);
            int t1 = id + __shfl_xor(id, 1);
            int t2 = t1 + __shfl_xor(t1, 2);
            float s = (float)t2 * (qs * KS);
            float p = valid ? __expf(s) : 0.f;
            denom += p;
            float ps = p * VS;
            cacc += ps;
            uint w;
            w = V.x;
            acc[0] = fmaf(ps, (float)(w & 0xff),         acc[0]);
            acc[1] = fmaf(ps, (float)((w >> 8) & 0xff),  acc[1]);
            acc[2] = fmaf(ps, (float)((w >> 16) & 0xff), acc[2]);
            acc[3] = fmaf(ps, (float)(w >> 24),          acc[3]);
            w = V.y;
            acc[4] = fmaf(ps, (float)(w & 0xff),         acc[4]);
            acc[5] = fmaf(ps, (float)((w >> 8) & 0xff),  acc[5]);
            acc[6] = fmaf(ps, (float)((w >> 16) & 0xff), acc[6]);
            acc[7] = fmaf(ps, (float)(w >> 24),          acc[7]);
        }
    }

    // undo +128 bias, then reduce over the 4 slots (lane bits 2,3) —
    // one pass retires all 4 nodes (nd bits untouched).
    #pragma unroll
    for (int i = 0; i < 8; ++i) acc[i] = fmaf(-128.f, cacc, acc[i]);
    #pragma unroll
    for (int i = 0; i < 8; ++i) {
        acc[i] += __shfl_xor(acc[i], 4);
        acc[i] += __shfl_xor(acc[i], 8);
    }
    denom += __shfl_xor(denom, 4);
    denom += __shfl_xor(denom, 8);

    if (slot == 0 && nv) {               // 16 lanes/wave: 4 nodes x 4 dg
        float inv = denom > 0.f ? 1.f / denom : 0.f;
        uint o[4];
        #pragma unroll
        for (int i = 0; i < 4; ++i)
            o[i] = (uint)f2bf(acc[2 * i] * inv) |
                   ((uint)f2bf(acc[2 * i + 1] * inv) << 16);
        char* ob = (char*)agg + (size_t)node * 512 + head * 64 + dg * 16;
        *(uint4*)ob = make_uint4(o[0], o[1], o[2], o[3]);
    }
}

extern "C" void kernel_launch(void* const* d_in, const int* in_sizes, int n_in,
                              void* d_out, int out_size, void* d_ws, size_t ws_size,
                              hipStream_t stream)
{
    const float* h  = (const float*)d_in[0];
    const int*   row = (const int*)d_in[1];
    const int*   col = (const int*)d_in[2];
    const float* Wq = (const float*)d_in[3];
    const float* bq = (const float*)d_in[4];
    const float* Wk = (const float*)d_in[5];
    const float* bk = (const float*)d_in[6];
    const float* Wv = (const float*)d_in[7];
    const float* bv = (const float*)d_in[8];
    const float* Wo = (const float*)d_in[9];
    const float* bo = (const float*)d_in[10];
    float* out = (float*)d_out;

    const int n = in_sizes[0] / 256;
    const int E = in_sizes[1];
    const size_t NC = (size_t)n * 256;

    char* base = (char*)d_ws;
    char*   q8h  = base;                                          // n*256 B
    uchar*  kvh  = (uchar*)(base + (size_t)n * 256);              // n*512 B
    float*  qs8  = (float*)(base + (size_t)n * 768);              // n*32 B
    float*  ks8  = (float*)(base + (size_t)n * 800);              // n*32 B
    float*  vs8  = (float*)(base + (size_t)n * 832);              // n*32 B
    ushort* aggb = (ushort*)(base + (size_t)n * 864);             // n*512 B
    ushort* hb   = (ushort*)(base + (size_t)n * 1376);            // n*512 B
    ushort* Wall = (ushort*)(base + (size_t)n * 1888);            // 384KB
    ushort* Wot  = Wall + 768 * 256;                              // 128KB
    float*  ball = (float*)(Wot + 65536);                         // 3KB
    int* row_ptr = (int*)(ball + 768);

    const float scaling = 0.17677669529663687f;  // 32^-0.5

    dim3 blk(256);
    prep<<<dim3(257, 5), blk, 0, stream>>>(Wq, Wk, Wv, Wo, bq, bk, bv,
                                           row, row_ptr, n, E,
                                           Wall, Wot, ball);
    convert_bf16<<<dim3((int)((NC / 4 + 255) / 256)), blk, 0, stream>>>(h, hb, NC);

    const int mtiles = (n + 127) / 128;
    gemm_mfma_lds<0><<<dim3(6, mtiles), blk, 0, stream>>>(
        hb, Wall, ball, q8h, qs8, kvh, ks8, vs8, nullptr, n, scaling);

    fused_attn<<<dim3(((n + 15) / 16) * 8), blk, 0, stream>>>(
        q8h, qs8, kvh, ks8, vs8, col, row_ptr, aggb, n);

    gemm_mfma_lds<1><<<dim3(2, mtiles), blk, 0, stream>>>(
        aggb, Wot, bo, nullptr, nullptr, nullptr, nullptr, nullptr, out, n, 1.f);
}